// Round 13
// baseline (210.264 us; speedup 1.0000x reference)
//
#include <hip/hip_runtime.h>
#include <math.h>

#define N_NODES 50000
#define N_EDGES 800000

typedef __attribute__((ext_vector_type(8))) short bf16x8;
typedef __attribute__((ext_vector_type(4))) float f32x4;

// round-to-nearest-even float -> bf16 (bits in low 16)
__device__ __forceinline__ unsigned f2bfu(float f) {
  union { float f; unsigned u; } v; v.f = f;
  return (v.u + 0x7FFFu + ((v.u >> 16) & 1u)) >> 16;
}
__device__ __forceinline__ short f2bf(float f) { return (short)f2bfu(f); }

__device__ __forceinline__ float bflo(unsigned d) {
  union { unsigned u; float f; } v; v.u = d << 16; return v.f;
}
__device__ __forceinline__ float bfhi(unsigned d) {
  union { unsigned u; float f; } v; v.u = d & 0xFFFF0000u; return v.f;
}

// tanh-gelu (jax approximate=True), exp2-folded (1/ln2 baked into constants).
// gelu(h) = h - h/(1+e), e = exp2(h*(a2*h^2 + b2)), a2=0.07135481/ln2*... :
//   2u = h*(0.14270962 h^2 + 1.59576912); exp(2u) = exp2(2u*1.44269504)
//   -> exp2(h*(0.20590551 h^2 + 2.30231120))
__device__ __forceinline__ float gelu_f(float h) {
  const float m1 = h * h;
  const float t2l = h * fmaf(0.10295276f, m1, 1.15115560f) * 2.f;
  const float e = exp2f(t2l);
  const float rc = __builtin_amdgcn_rcpf(1.f + e);
  return h - h * rc;
}

#define PIN(v) asm volatile("" : "+v"(v))

// ---------------------------------------------------------------------------
// Kernel 0: build bf16 MFMA weight fragments once (16 KB in ws).
//   wfrag[id], id = mat*512 + mb*64 + lane; lane=(gg<<4)|rr
//   frag[t] = W[(gg*8+t)*128 + 16*mb + rr]  (k=31 pad -> 0)
//   mat 0: W1e (rows 256..286 of W1)
//   mat 1: W_proj, with k=31 slot = b_proj[col] (activated by eb[31]=1.0)
// ---------------------------------------------------------------------------
__global__ void wfrag_kernel(const float* __restrict__ W_proj,
                             const float* __restrict__ W1,
                             const float* __restrict__ b_proj,
                             uint4* __restrict__ wfrag) {
  const int id = threadIdx.x;            // 0..1023
  const int mat = id >> 9;
  const int fid = id & 511;
  const int mb = fid >> 6, ln = fid & 63;
  const int rr = ln & 15, gg = ln >> 4;
  const float* W = mat ? W_proj : (W1 + (size_t)256 * 128);
  union { uint4 u; bf16x8 b; } f;
#pragma unroll
  for (int t = 0; t < 8; ++t) {
    const int kk = gg * 8 + t;
    float v = 0.f;
    if (kk < 31) v = W[(size_t)kk * 128 + 16 * mb + rr];
    else if (mat == 1 && kk == 31) v = b_proj[16 * mb + rr];
    f.b[t] = f2bf(v);
  }
  wfrag[id] = f.u;
}

// ---------------------------------------------------------------------------
// Kernel 1: AB (bf16, fragment-major layout) — unchanged (round-7 proven).
//   ushort offset: n*256 + half*128 + g4*32 + mb8*4 + i
//   value = x[n] . Wab[:,c] + 0.5*b1[c mod 128]
// ---------------------------------------------------------------------------
__global__ __launch_bounds__(256) void node_kernel(
    const float* __restrict__ x, const float* __restrict__ W1,
    const float* __restrict__ b1, unsigned short* __restrict__ AB) {
  const int l = threadIdx.x & 63;
  const int wv = threadIdx.x >> 6;
  const int r = l & 15, g4 = l >> 4;

  const int wid = blockIdx.x * 4 + wv;
  const int s = wid & 3;                 // col strip: blocks mb = 4s+q

  bf16x8 wA[4][4];
#pragma unroll
  for (int q = 0; q < 4; ++q) {
    const int c = 16 * (4 * s + q) + r;
    const float* Wb = (c < 128) ? (W1 + c) : (W1 + 128 * 128 + (c - 128));
#pragma unroll
    for (int ks = 0; ks < 4; ++ks) {
#pragma unroll
      for (int t = 0; t < 8; ++t)
        wA[q][ks][t] = f2bf(Wb[(size_t)(ks * 32 + g4 * 8 + t) * 128]);
      PIN(wA[q][ks]);
    }
  }
  float4 bv[4];
#pragma unroll
  for (int q = 0; q < 4; ++q)
    bv[q] = *(const float4*)(b1 + ((16 * (4 * s + q) + g4 * 4) & 127));

  const int half = s >> 1;

  for (int t0 = wid >> 2; t0 < (N_NODES / 16); t0 += 1024) {
    const int n0 = t0 * 16;
    f32x4 acc[4] = {{0,0,0,0},{0,0,0,0},{0,0,0,0},{0,0,0,0}};
#pragma unroll
    for (int ks = 0; ks < 4; ++ks) {
      const float* xr = x + (size_t)(n0 + r) * 128 + ks * 32 + g4 * 8;
      const float4 x0 = *(const float4*)xr;
      const float4 x1 = *(const float4*)(xr + 4);
      bf16x8 xb;
      xb[0] = f2bf(x0.x); xb[1] = f2bf(x0.y); xb[2] = f2bf(x0.z); xb[3] = f2bf(x0.w);
      xb[4] = f2bf(x1.x); xb[5] = f2bf(x1.y); xb[6] = f2bf(x1.z); xb[7] = f2bf(x1.w);
#pragma unroll
      for (int q = 0; q < 4; ++q)
        acc[q] = __builtin_amdgcn_mfma_f32_16x16x32_bf16(wA[q][ks], xb, acc[q], 0, 0, 0);
    }
#pragma unroll
    for (int q = 0; q < 4; ++q) {
      const int mb8 = 4 * (s & 1) + q;
      const float o0 = acc[q][0] + 0.5f * bv[q].x;
      const float o1 = acc[q][1] + 0.5f * bv[q].y;
      const float o2 = acc[q][2] + 0.5f * bv[q].z;
      const float o3 = acc[q][3] + 0.5f * bv[q].w;
      uint2 pk;
      pk.x = f2bfu(o0) | (f2bfu(o1) << 16);
      pk.y = f2bfu(o2) | (f2bfu(o3) << 16);
      *(uint2*)(AB + (size_t)(n0 + r) * 256 + half * 128 + g4 * 32 + mb8 * 4) = pk;
    }
  }
}

// ---------------------------------------------------------------------------
// Kernel 2: fused edge kernel — round-13: r12 pipeline + streaming loads nt.
//  - ea rows + edge_index loaded nontemporal (read-once; stop these streams
//    from evicting the 25.6 MB AB table out of L2/L3 between gathers)
//  - AB gathers stay cached (the only data with reuse)
//  - everything else identical to round 12 (depth-2 vmcnt-clean pipeline,
//    wP in LDS, b_proj baked, swizzled tlds, contiguous nt stores)
// ---------------------------------------------------------------------------
__global__ __launch_bounds__(256) void edge_kernel(
    const float* __restrict__ edge_attr, const int* __restrict__ edge_index,
    const unsigned short* __restrict__ AB, const uint4* __restrict__ wfrag,
    const float* __restrict__ W2, const float* __restrict__ b2,
    float* __restrict__ out) {
  __shared__ float tlds[4][16 * 128];   // 32 KB
  __shared__ uint4 wPl[512];            // 8 KB
  const int tid = threadIdx.x;
  const int l = tid & 63;
  const int wv = tid >> 6;
  const int r = l & 15, g4 = l >> 4;
  float* const tl = &tlds[wv][0];

  // stage wP fragments into LDS (one shot)
  wPl[tid] = wfrag[512 + tid];
  wPl[tid + 256] = wfrag[768 + tid];

  bf16x8 wH[8];
#pragma unroll
  for (int mb = 0; mb < 8; ++mb) {
    union { uint4 u; bf16x8 b; } h;
    h.u = wfrag[mb * 64 + l];
    wH[mb] = h.b;
    PIN(wH[mb]);
  }
  const float b2v = b2[0];
  __syncthreads();

  const int nwaves = gridDim.x * 4;
  const int NT = N_EDGES / 16;

  int tile = blockIdx.x * 4 + wv;
  if (tile >= NT) return;

  // ---- prologue: gathers+ea for tile; idx for tile+nw in flight ----
  int sA, dA;
  uint4 ua[4], ub[4];
  float ear[8];
  {
    const int e = tile * 16 + r;
    const int cs = __builtin_nontemporal_load(edge_index + e);
    const int cd = __builtin_nontemporal_load(edge_index + N_EDGES + e);
    const uint4* ap4 = (const uint4*)(AB + (size_t)cs * 256 + g4 * 32);
    const uint4* bp4 = (const uint4*)(AB + (size_t)cd * 256 + 128 + g4 * 32);
#pragma unroll
    for (int t = 0; t < 4; ++t) { ua[t] = ap4[t]; ub[t] = bp4[t]; }
    const float* earp = edge_attr + (size_t)e * 31 + g4 * 8;
#pragma unroll
    for (int t = 0; t < 8; ++t)
      ear[t] = (g4 * 8 + t < 31) ? __builtin_nontemporal_load(earp + t) : 0.f;
    const int tn = tile + nwaves;
    const int en = (tn < NT ? tn : tile) * 16 + r;
    sA = __builtin_nontemporal_load(edge_index + en);
    dA = __builtin_nontemporal_load(edge_index + N_EDGES + en);
  }

  for (; tile < NT; tile += nwaves) {
    const int tn = tile + nwaves;
    const int tn2 = tile + 2 * nwaves;

    // issue idx(tile + 2*nw) now; consumed next iteration
    const int en2 = (tn2 < NT ? tn2 : tile) * 16 + r;
    const int sB = __builtin_nontemporal_load(edge_index + en2);
    const int dB = __builtin_nontemporal_load(edge_index + N_EDGES + en2);

    // pack eb (consumes ear); k=31 slot = 1.0 to activate baked b_proj
    bf16x8 eb;
#pragma unroll
    for (int t = 0; t < 8; ++t) eb[t] = f2bf(ear[t]);
    if (g4 == 3) eb[7] = (short)0x3F80;

    // unpack + combine gathers (consumes ua/ub)
    f32x4 acch[8];
#pragma unroll
    for (int t = 0; t < 4; ++t) {
      acch[2 * t][0]     = bflo(ua[t].x) + bflo(ub[t].x);
      acch[2 * t][1]     = bfhi(ua[t].x) + bfhi(ub[t].x);
      acch[2 * t][2]     = bflo(ua[t].y) + bflo(ub[t].y);
      acch[2 * t][3]     = bfhi(ua[t].y) + bfhi(ub[t].y);
      acch[2 * t + 1][0] = bflo(ua[t].z) + bflo(ub[t].z);
      acch[2 * t + 1][1] = bfhi(ua[t].z) + bfhi(ub[t].z);
      acch[2 * t + 1][2] = bflo(ua[t].w) + bflo(ub[t].w);
      acch[2 * t + 1][3] = bfhi(ua[t].w) + bfhi(ub[t].w);
    }

    // issue NEXT tile's gathers + ea now (oldest-in-queue before stores)
    if (tn < NT) {
      const uint4* ap4 = (const uint4*)(AB + (size_t)sA * 256 + g4 * 32);
      const uint4* bp4 = (const uint4*)(AB + (size_t)dA * 256 + 128 + g4 * 32);
#pragma unroll
      for (int t = 0; t < 4; ++t) { ua[t] = ap4[t]; ub[t] = bp4[t]; }
      const float* earp = edge_attr + (size_t)(tn * 16 + r) * 31 + g4 * 8;
#pragma unroll
      for (int t = 0; t < 8; ++t)
        if (g4 * 8 + t < 31) ear[t] = __builtin_nontemporal_load(earp + t);
    }

    // h-path MFMA
#pragma unroll
    for (int mb = 0; mb < 8; ++mb)
      acch[mb] = __builtin_amdgcn_mfma_f32_16x16x32_bf16(wH[mb], eb, acch[mb], 0, 0, 0);

    // gate logit: lane holds cols j = 16*mb + g4*4 + i of its edge
    float lg = 0.f;
#pragma unroll
    for (int mb = 0; mb < 8; ++mb) {
      const float4 w2v = *(const float4*)(W2 + 16 * mb + 4 * g4);
      lg = fmaf(gelu_f(acch[mb][0]), w2v.x, lg);
      lg = fmaf(gelu_f(acch[mb][1]), w2v.y, lg);
      lg = fmaf(gelu_f(acch[mb][2]), w2v.z, lg);
      lg = fmaf(gelu_f(acch[mb][3]), w2v.w, lg);
    }
    lg += __shfl_xor(lg, 16);
    lg += __shfl_xor(lg, 32);
    // sigmoid, exp2-folded
    const float gate =
        __builtin_amdgcn_rcpf(1.f + exp2f(-1.44269504f * (lg + b2v)));

    // anti-LICM: force per-iteration LDS reads of wP (keeps them off VGPRs)
    unsigned zoff = 0;
    PIN(zoff);

    // base projection from LDS wP (b_proj baked) -> swizzled LDS tile
#pragma unroll
    for (int mb = 0; mb < 8; ++mb) {
      union { uint4 u; bf16x8 b; } wp;
      wp.u = wPl[mb * 64 + l + zoff];
      f32x4 ac = __builtin_amdgcn_mfma_f32_16x16x32_bf16(
          wp.b, eb, (f32x4){0.f, 0.f, 0.f, 0.f}, 0, 0, 0);
      f32x4 o;
      o[0] = ac[0] * gate;
      o[1] = ac[1] * gate;
      o[2] = ac[2] * gate;
      o[3] = ac[3] * gate;
      const int col = 16 * mb + 4 * g4;
      *(f32x4*)(tl + 128 * r + (col ^ ((r & 7) << 2))) = o;
    }

    // transposed readback -> each nt store covers contiguous 1 KB
    float* const obase = out + (size_t)tile * 16 * 128;
#pragma unroll
    for (int k = 0; k < 8; ++k) {
      const int row = 2 * k + (l >> 5);
      const int col = 4 * (l & 31);
      const f32x4 v = *(const f32x4*)(tl + 128 * row + (col ^ ((row & 7) << 2)));
      __builtin_nontemporal_store(v, (f32x4*)(obase + 256 * k + 4 * l));
    }

    sA = sB; dA = dB;
  }
}

extern "C" void kernel_launch(void* const* d_in, const int* in_sizes, int n_in,
                              void* d_out, int out_size, void* d_ws, size_t ws_size,
                              hipStream_t stream) {
  const float* x          = (const float*)d_in[0];
  const float* edge_attr  = (const float*)d_in[1];
  const int*   edge_index = (const int*)d_in[2];
  const float* W_proj     = (const float*)d_in[3];
  const float* b_proj     = (const float*)d_in[4];
  const float* W1         = (const float*)d_in[5];
  const float* b1         = (const float*)d_in[6];
  const float* W2         = (const float*)d_in[7];
  const float* b2         = (const float*)d_in[8];
  float* out = (float*)d_out;
  unsigned short* AB = (unsigned short*)d_ws;           // 25.6 MB
  uint4* wfrag = (uint4*)(AB + (size_t)N_NODES * 256);  // 16 KB, 16B-aligned

  hipLaunchKernelGGL(wfrag_kernel, dim3(1), dim3(1024), 0, stream,
                     W_proj, W1, b_proj, wfrag);
  hipLaunchKernelGGL(node_kernel, dim3(1024), dim3(256), 0, stream,
                     x, W1, b1, AB);
  hipLaunchKernelGGL(edge_kernel, dim3(2048), dim3(256), 0, stream,
                     edge_attr, edge_index, AB, wfrag, W2, b2,
                     out);
}

// Round 14
// 166.284 us; speedup vs baseline: 1.2645x; 1.2645x over previous
//
#include <hip/hip_runtime.h>
#include <math.h>

#define N_NODES 50000
#define N_EDGES 800000

typedef __attribute__((ext_vector_type(8))) short bf16x8;
typedef __attribute__((ext_vector_type(4))) float f32x4;

// round-to-nearest-even float -> bf16 (bits in low 16)
__device__ __forceinline__ unsigned f2bfu(float f) {
  union { float f; unsigned u; } v; v.f = f;
  return (v.u + 0x7FFFu + ((v.u >> 16) & 1u)) >> 16;
}
__device__ __forceinline__ short f2bf(float f) { return (short)f2bfu(f); }

__device__ __forceinline__ float bflo(unsigned d) {
  union { unsigned u; float f; } v; v.u = d << 16; return v.f;
}
__device__ __forceinline__ float bfhi(unsigned d) {
  union { unsigned u; float f; } v; v.u = d & 0xFFFF0000u; return v.f;
}

// tanh-gelu (jax approximate=True), exp2 direct:
//   exp(2u) = exp2(h*(0.10295276 h^2 + 2.30231120))   [1/ln2 folded]
__device__ __forceinline__ float gelu_f(float h) {
  const float m1 = h * h;
  const float a = h * fmaf(0.10295276f, m1, 2.30231120f);
  const float e = exp2f(a);
  const float rc = __builtin_amdgcn_rcpf(1.f + e);
  return h - h * rc;
}

#define PIN(v) asm volatile("" : "+v"(v))

// ---------------------------------------------------------------------------
// Kernel 0: build bf16 MFMA weight fragments once (16 KB in ws).
//   wfrag[id], id = mat*512 + mb*64 + lane; lane=(gg<<4)|rr
//   frag[t] = W[(gg*8+t)*128 + 16*mb + rr]  (k=31 pad -> 0)
//   mat 0: W1e (rows 256..286 of W1)
//   mat 1: W_proj, with k=31 slot = b_proj[col] (activated by eb[31]=1.0)
// ---------------------------------------------------------------------------
__global__ void wfrag_kernel(const float* __restrict__ W_proj,
                             const float* __restrict__ W1,
                             const float* __restrict__ b_proj,
                             uint4* __restrict__ wfrag) {
  const int id = threadIdx.x;            // 0..1023
  const int mat = id >> 9;
  const int fid = id & 511;
  const int mb = fid >> 6, ln = fid & 63;
  const int rr = ln & 15, gg = ln >> 4;
  const float* W = mat ? W_proj : (W1 + (size_t)256 * 128);
  union { uint4 u; bf16x8 b; } f;
#pragma unroll
  for (int t = 0; t < 8; ++t) {
    const int kk = gg * 8 + t;
    float v = 0.f;
    if (kk < 31) v = W[(size_t)kk * 128 + 16 * mb + rr];
    else if (mat == 1 && kk == 31) v = b_proj[16 * mb + rr];
    f.b[t] = f2bf(v);
  }
  wfrag[id] = f.u;
}

// ---------------------------------------------------------------------------
// Kernel 1: AB (bf16, fragment-major) — round-14: block-shared x staging.
// The 4 waves of a block process the SAME node-tile (strips s=wv); the x
// tile is staged once into padded LDS (was 4x redundant HBM reads of x).
//   ushort offset: n*256 + half*128 + g4*32 + mb8*4 + i
//   value = x[n] . Wab[:,c] + 0.5*b1[c mod 128]
// ---------------------------------------------------------------------------
__global__ __launch_bounds__(256) void node_kernel(
    const float* __restrict__ x, const float* __restrict__ W1,
    const float* __restrict__ b1, unsigned short* __restrict__ AB) {
  __shared__ float xs[16 * 132];         // padded row stride 132 dwords
  const int tid = threadIdx.x;
  const int l = tid & 63;
  const int wv = tid >> 6;
  const int r = l & 15, g4 = l >> 4;

  const int s = wv;                      // col strip: blocks mb = 4s+q
  bf16x8 wA[4][4];
#pragma unroll
  for (int q = 0; q < 4; ++q) {
    const int c = 16 * (4 * s + q) + r;
    const float* Wb = (c < 128) ? (W1 + c) : (W1 + 128 * 128 + (c - 128));
#pragma unroll
    for (int ks = 0; ks < 4; ++ks) {
#pragma unroll
      for (int t = 0; t < 8; ++t)
        wA[q][ks][t] = f2bf(Wb[(size_t)(ks * 32 + g4 * 8 + t) * 128]);
      PIN(wA[q][ks]);
    }
  }
  float4 bv[4];
#pragma unroll
  for (int q = 0; q < 4; ++q)
    bv[q] = *(const float4*)(b1 + ((16 * (4 * s + q) + g4 * 4) & 127));

  const int half = s >> 1;
  // staging map: thread tid covers row=tid>>4, cols (tid&15)*8 .. +8
  const int srow = tid >> 4, scol = (tid & 15) * 8;

  for (int t0 = blockIdx.x; t0 < (N_NODES / 16); t0 += gridDim.x) {
    const int n0 = t0 * 16;
    const float4 xa = *(const float4*)(x + (size_t)(n0 + srow) * 128 + scol);
    const float4 xb4 = *(const float4*)(x + (size_t)(n0 + srow) * 128 + scol + 4);
    __syncthreads();   // previous tile's readers done
    *(float4*)(xs + srow * 132 + scol) = xa;
    *(float4*)(xs + srow * 132 + scol + 4) = xb4;
    __syncthreads();   // writers done

    f32x4 acc[4] = {{0,0,0,0},{0,0,0,0},{0,0,0,0},{0,0,0,0}};
#pragma unroll
    for (int ks = 0; ks < 4; ++ks) {
      const float* xr = xs + r * 132 + ks * 32 + g4 * 8;
      const float4 x0 = *(const float4*)xr;
      const float4 x1 = *(const float4*)(xr + 4);
      bf16x8 xv;
      xv[0] = f2bf(x0.x); xv[1] = f2bf(x0.y); xv[2] = f2bf(x0.z); xv[3] = f2bf(x0.w);
      xv[4] = f2bf(x1.x); xv[5] = f2bf(x1.y); xv[6] = f2bf(x1.z); xv[7] = f2bf(x1.w);
#pragma unroll
      for (int q = 0; q < 4; ++q)
        acc[q] = __builtin_amdgcn_mfma_f32_16x16x32_bf16(wA[q][ks], xv, acc[q], 0, 0, 0);
    }
#pragma unroll
    for (int q = 0; q < 4; ++q) {
      const int mb8 = 4 * (s & 1) + q;
      const float o0 = acc[q][0] + 0.5f * bv[q].x;
      const float o1 = acc[q][1] + 0.5f * bv[q].y;
      const float o2 = acc[q][2] + 0.5f * bv[q].z;
      const float o3 = acc[q][3] + 0.5f * bv[q].w;
      uint2 pk;
      pk.x = f2bfu(o0) | (f2bfu(o1) << 16);
      pk.y = f2bfu(o2) | (f2bfu(o3) << 16);
      *(uint2*)(AB + (size_t)(n0 + r) * 256 + half * 128 + g4 * 32 + mb8 * 4) = pk;
    }
  }
}

// ---------------------------------------------------------------------------
// Kernel 2: fused edge kernel — exact round-12 structure (best: 171.4 us),
// with plain (cached) idx/ea loads, corrected exp2-folded gelu/sigmoid,
// and grid 1024 (all blocks resident in one batch, single prologue).
// ---------------------------------------------------------------------------
__global__ __launch_bounds__(256) void edge_kernel(
    const float* __restrict__ edge_attr, const int* __restrict__ edge_index,
    const unsigned short* __restrict__ AB, const uint4* __restrict__ wfrag,
    const float* __restrict__ W2, const float* __restrict__ b2,
    float* __restrict__ out) {
  __shared__ float tlds[4][16 * 128];   // 32 KB
  __shared__ uint4 wPl[512];            // 8 KB
  const int tid = threadIdx.x;
  const int l = tid & 63;
  const int wv = tid >> 6;
  const int r = l & 15, g4 = l >> 4;
  float* const tl = &tlds[wv][0];

  // stage wP fragments into LDS (one shot)
  wPl[tid] = wfrag[512 + tid];
  wPl[tid + 256] = wfrag[768 + tid];

  bf16x8 wH[8];
#pragma unroll
  for (int mb = 0; mb < 8; ++mb) {
    union { uint4 u; bf16x8 b; } h;
    h.u = wfrag[mb * 64 + l];
    wH[mb] = h.b;
    PIN(wH[mb]);
  }
  const float b2v = b2[0];
  __syncthreads();

  const int nwaves = gridDim.x * 4;
  const int NT = N_EDGES / 16;

  int tile = blockIdx.x * 4 + wv;
  if (tile >= NT) return;

  // ---- prologue: gathers+ea for tile; idx for tile+nw in flight ----
  int sA, dA;
  uint4 ua[4], ub[4];
  float ear[8];
  {
    const int e = tile * 16 + r;
    const int cs = edge_index[e];
    const int cd = edge_index[N_EDGES + e];
    const uint4* ap4 = (const uint4*)(AB + (size_t)cs * 256 + g4 * 32);
    const uint4* bp4 = (const uint4*)(AB + (size_t)cd * 256 + 128 + g4 * 32);
#pragma unroll
    for (int t = 0; t < 4; ++t) { ua[t] = ap4[t]; ub[t] = bp4[t]; }
    const float* earp = edge_attr + (size_t)e * 31 + g4 * 8;
#pragma unroll
    for (int t = 0; t < 8; ++t)
      ear[t] = (g4 * 8 + t < 31) ? earp[t] : 0.f;
    const int tn = tile + nwaves;
    const int en = (tn < NT ? tn : tile) * 16 + r;
    sA = edge_index[en];
    dA = edge_index[N_EDGES + en];
  }

  for (; tile < NT; tile += nwaves) {
    const int tn = tile + nwaves;
    const int tn2 = tile + 2 * nwaves;

    // issue idx(tile + 2*nw) now; consumed next iteration
    const int en2 = (tn2 < NT ? tn2 : tile) * 16 + r;
    const int sB = edge_index[en2];
    const int dB = edge_index[N_EDGES + en2];

    // pack eb (consumes ear); k=31 slot = 1.0 to activate baked b_proj
    bf16x8 eb;
#pragma unroll
    for (int t = 0; t < 8; ++t) eb[t] = f2bf(ear[t]);
    if (g4 == 3) eb[7] = (short)0x3F80;

    // unpack + combine gathers (consumes ua/ub)
    f32x4 acch[8];
#pragma unroll
    for (int t = 0; t < 4; ++t) {
      acch[2 * t][0]     = bflo(ua[t].x) + bflo(ub[t].x);
      acch[2 * t][1]     = bfhi(ua[t].x) + bfhi(ub[t].x);
      acch[2 * t][2]     = bflo(ua[t].y) + bflo(ub[t].y);
      acch[2 * t][3]     = bfhi(ua[t].y) + bfhi(ub[t].y);
      acch[2 * t + 1][0] = bflo(ua[t].z) + bflo(ub[t].z);
      acch[2 * t + 1][1] = bfhi(ua[t].z) + bfhi(ub[t].z);
      acch[2 * t + 1][2] = bflo(ua[t].w) + bflo(ub[t].w);
      acch[2 * t + 1][3] = bfhi(ua[t].w) + bfhi(ub[t].w);
    }

    // issue NEXT tile's gathers + ea now (oldest-in-queue before stores)
    if (tn < NT) {
      const uint4* ap4 = (const uint4*)(AB + (size_t)sA * 256 + g4 * 32);
      const uint4* bp4 = (const uint4*)(AB + (size_t)dA * 256 + 128 + g4 * 32);
#pragma unroll
      for (int t = 0; t < 4; ++t) { ua[t] = ap4[t]; ub[t] = bp4[t]; }
      const float* earp = edge_attr + (size_t)(tn * 16 + r) * 31 + g4 * 8;
#pragma unroll
      for (int t = 0; t < 8; ++t)
        if (g4 * 8 + t < 31) ear[t] = earp[t];
    }

    // h-path MFMA
#pragma unroll
    for (int mb = 0; mb < 8; ++mb)
      acch[mb] = __builtin_amdgcn_mfma_f32_16x16x32_bf16(wH[mb], eb, acch[mb], 0, 0, 0);

    // gate logit: lane holds cols j = 16*mb + g4*4 + i of its edge
    float lg = 0.f;
#pragma unroll
    for (int mb = 0; mb < 8; ++mb) {
      const float4 w2v = *(const float4*)(W2 + 16 * mb + 4 * g4);
      lg = fmaf(gelu_f(acch[mb][0]), w2v.x, lg);
      lg = fmaf(gelu_f(acch[mb][1]), w2v.y, lg);
      lg = fmaf(gelu_f(acch[mb][2]), w2v.z, lg);
      lg = fmaf(gelu_f(acch[mb][3]), w2v.w, lg);
    }
    lg += __shfl_xor(lg, 16);
    lg += __shfl_xor(lg, 32);
    // sigmoid, exp2-folded
    const float gate =
        __builtin_amdgcn_rcpf(1.f + exp2f(-1.44269504f * (lg + b2v)));

    // anti-LICM: force per-iteration LDS reads of wP (keeps them off VGPRs)
    unsigned zoff = 0;
    PIN(zoff);

    // base projection from LDS wP (b_proj baked) -> swizzled LDS tile
#pragma unroll
    for (int mb = 0; mb < 8; ++mb) {
      union { uint4 u; bf16x8 b; } wp;
      wp.u = wPl[mb * 64 + l + zoff];
      f32x4 ac = __builtin_amdgcn_mfma_f32_16x16x32_bf16(
          wp.b, eb, (f32x4){0.f, 0.f, 0.f, 0.f}, 0, 0, 0);
      f32x4 o;
      o[0] = ac[0] * gate;
      o[1] = ac[1] * gate;
      o[2] = ac[2] * gate;
      o[3] = ac[3] * gate;
      const int col = 16 * mb + 4 * g4;
      *(f32x4*)(tl + 128 * r + (col ^ ((r & 7) << 2))) = o;
    }

    // transposed readback -> each nt store covers contiguous 1 KB
    float* const obase = out + (size_t)tile * 16 * 128;
#pragma unroll
    for (int k = 0; k < 8; ++k) {
      const int row = 2 * k + (l >> 5);
      const int col = 4 * (l & 31);
      const f32x4 v = *(const f32x4*)(tl + 128 * row + (col ^ ((row & 7) << 2)));
      __builtin_nontemporal_store(v, (f32x4*)(obase + 256 * k + 4 * l));
    }

    sA = sB; dA = dB;
  }
}

extern "C" void kernel_launch(void* const* d_in, const int* in_sizes, int n_in,
                              void* d_out, int out_size, void* d_ws, size_t ws_size,
                              hipStream_t stream) {
  const float* x          = (const float*)d_in[0];
  const float* edge_attr  = (const float*)d_in[1];
  const int*   edge_index = (const int*)d_in[2];
  const float* W_proj     = (const float*)d_in[3];
  const float* b_proj     = (const float*)d_in[4];
  const float* W1         = (const float*)d_in[5];
  const float* b1         = (const float*)d_in[6];
  const float* W2         = (const float*)d_in[7];
  const float* b2         = (const float*)d_in[8];
  float* out = (float*)d_out;
  unsigned short* AB = (unsigned short*)d_ws;           // 25.6 MB
  uint4* wfrag = (uint4*)(AB + (size_t)N_NODES * 256);  // 16 KB, 16B-aligned

  hipLaunchKernelGGL(wfrag_kernel, dim3(1), dim3(1024), 0, stream,
                     W_proj, W1, b_proj, wfrag);
  hipLaunchKernelGGL(node_kernel, dim3(1024), dim3(256), 0, stream,
                     x, W1, b1, AB);
  hipLaunchKernelGGL(edge_kernel, dim3(1024), dim3(256), 0, stream,
                     edge_attr, edge_index, AB, wfrag, W2, b2,
                     out);
}